// Round 1
// baseline (3781.702 us; speedup 1.0000x reference)
//
#include <hip/hip_runtime.h>
#include <hip/hip_bf16.h>

constexpr int Bb = 4, Ss = 8192, Dd = 1024, Hh = 16, DK = 64;
constexpr int Mrows = Bb * Ss;   // 32768

// ---------------- GEMM: Y = act(X @ W^T) ----------------
// X: [M,K] row-major, W: [N,K] row-major (so contraction is over the fast dim
// of both — "NT" layout). 128x128 tile, BK=16, 8x8 micro-tile per thread.
template<int ACT>
__global__ __launch_bounds__(256)
void gemm_xt(const float* __restrict__ X, const float* __restrict__ W,
             float* __restrict__ Y, int M, int N, int K)
{
    __shared__ float As[16][128];   // [k][m] (transposed on store)
    __shared__ float Bs[16][128];   // [k][n]
    const int t  = threadIdx.x;
    const int tx = t & 15;          // n sub-tile
    const int ty = t >> 4;          // m sub-tile
    const int m0 = blockIdx.x * 128;
    const int n0 = blockIdx.y * 128;

    float acc[8][8];
#pragma unroll
    for (int i = 0; i < 8; ++i)
#pragma unroll
        for (int j = 0; j < 8; ++j) acc[i][j] = 0.f;

    for (int k0 = 0; k0 < K; k0 += 16) {
        // stage 128 rows x 16 k of each operand; 512 float4 per matrix,
        // 2 per thread; transpose into [k][row]
#pragma unroll
        for (int l = 0; l < 2; ++l) {
            const int i   = t + l * 256;     // [0,512)
            const int row = i >> 2;          // [0,128)
            const int c4  = (i & 3) << 2;    // {0,4,8,12}
            const float4 av = *(const float4*)&X[(size_t)(m0 + row) * K + k0 + c4];
            const float4 bv = *(const float4*)&W[(size_t)(n0 + row) * K + k0 + c4];
            As[c4 + 0][row] = av.x; As[c4 + 1][row] = av.y;
            As[c4 + 2][row] = av.z; As[c4 + 3][row] = av.w;
            Bs[c4 + 0][row] = bv.x; Bs[c4 + 1][row] = bv.y;
            Bs[c4 + 2][row] = bv.z; Bs[c4 + 3][row] = bv.w;
        }
        __syncthreads();
#pragma unroll
        for (int kk = 0; kk < 16; ++kk) {
            const float4 a0 = *(const float4*)&As[kk][ty * 8];
            const float4 a1 = *(const float4*)&As[kk][ty * 8 + 4];
            const float4 b0 = *(const float4*)&Bs[kk][tx * 8];
            const float4 b1 = *(const float4*)&Bs[kk][tx * 8 + 4];
            const float a[8]  = {a0.x, a0.y, a0.z, a0.w, a1.x, a1.y, a1.z, a1.w};
            const float bb[8] = {b0.x, b0.y, b0.z, b0.w, b1.x, b1.y, b1.z, b1.w};
#pragma unroll
            for (int i = 0; i < 8; ++i)
#pragma unroll
                for (int j = 0; j < 8; ++j)
                    acc[i][j] = fmaf(a[i], bb[j], acc[i][j]);
        }
        __syncthreads();
    }

#pragma unroll
    for (int i = 0; i < 8; ++i) {
        float vals[8];
#pragma unroll
        for (int j = 0; j < 8; ++j) {
            float v = acc[i][j];
            if (ACT) v = fmaxf(v, 0.f) + 1e-6f;
            vals[j] = v;
        }
        float* yp = &Y[(size_t)(m0 + ty * 8 + i) * N + n0 + tx * 8];
        *(float4*)(yp)     = make_float4(vals[0], vals[1], vals[2], vals[3]);
        *(float4*)(yp + 4) = make_float4(vals[4], vals[5], vals[6], vals[7]);
    }
}

// ---------------- kv = sum_s K[s,d] * V[s,e] per (b,h), + k_totsum ----------
constexpr int SUB2 = 64;     // rows staged per sub-chunk
constexpr int CH2  = 1024;   // rows per block

__global__ __launch_bounds__(256)
void kv_kernel(const float* __restrict__ Kp, const float* __restrict__ Vp,
               float* __restrict__ kv, float* __restrict__ ksum)
{
    __shared__ float Kc[SUB2][64];
    __shared__ float Vc[SUB2][64];
    const int bh = blockIdx.x;           // [0, B*H)
    const int b = bh >> 4, h = bh & 15;
    const int chunk = blockIdx.y;        // [0, S/CH2)
    const int t = threadIdx.x;
    const int dt = (t >> 4) << 2;        // d tile base: 4 rows
    const int et = (t & 15) << 2;        // e tile base: 4 cols
    const size_t base_row = (size_t)b * Ss + (size_t)chunk * CH2;
    const int col0 = h * DK;

    float acc[4][4];
#pragma unroll
    for (int i = 0; i < 4; ++i)
#pragma unroll
        for (int j = 0; j < 4; ++j) acc[i][j] = 0.f;
    float ks_local = 0.f;

    for (int sub = 0; sub < CH2 / SUB2; ++sub) {
#pragma unroll
        for (int l = 0; l < 4; ++l) {
            const int i   = t + l * 256;    // [0,1024)
            const int row = i >> 4;         // [0,64)
            const int c   = (i & 15) << 2;  // [0,64) step 4
            const size_t g = (base_row + (size_t)sub * SUB2 + row) * Dd + col0 + c;
            const float4 kvv = *(const float4*)&Kp[g];
            const float4 vvv = *(const float4*)&Vp[g];
            *(float4*)&Kc[row][c] = kvv;
            *(float4*)&Vc[row][c] = vvv;
            ks_local += kvv.x + kvv.y + kvv.z + kvv.w;
        }
        __syncthreads();
#pragma unroll 8
        for (int s = 0; s < SUB2; ++s) {
            const float4 kd = *(const float4*)&Kc[s][dt];
            const float4 ve = *(const float4*)&Vc[s][et];
            const float ka[4] = {kd.x, kd.y, kd.z, kd.w};
            const float vb[4] = {ve.x, ve.y, ve.z, ve.w};
#pragma unroll
            for (int i = 0; i < 4; ++i)
#pragma unroll
                for (int j = 0; j < 4; ++j)
                    acc[i][j] = fmaf(ka[i], vb[j], acc[i][j]);
        }
        __syncthreads();
    }
#pragma unroll
    for (int i = 0; i < 4; ++i)
#pragma unroll
        for (int j = 0; j < 4; ++j)
            atomicAdd(&kv[(size_t)bh * 4096 + (size_t)(dt + i) * 64 + et + j],
                      acc[i][j]);

    // k_totsum: wave reduce, one atomic per wave
#pragma unroll
    for (int off = 32; off > 0; off >>= 1)
        ks_local += __shfl_down(ks_local, off, 64);
    if ((t & 63) == 0) atomicAdd(&ksum[bh], ks_local);
}

// ------------- qkv = Q @ kv per (b,h), fused normalizer -> O ---------------
__global__ __launch_bounds__(256)
void qkv_norm_kernel(const float* __restrict__ Q, const float* __restrict__ kv,
                     const float* __restrict__ ksum, float* __restrict__ O)
{
    __shared__ float kvs[64][64];
    const int bh = blockIdx.x;
    const int b = bh >> 4, h = bh & 15;
    const int chunk = blockIdx.y;        // [0, S/64)
    const int t = threadIdx.x;
#pragma unroll
    for (int l = 0; l < 16; ++l) {
        const int i = t + l * 256;
        kvs[i >> 6][i & 63] = kv[(size_t)bh * 4096 + i];
    }
    const float ks = ksum[bh];
    __syncthreads();
    const int sl = t >> 6;               // which of 4 rows this wave owns
    const int e  = t & 63;
    for (int s4 = 0; s4 < 16; ++s4) {
        const int srow = chunk * 64 + s4 * 4 + sl;
        const size_t g = ((size_t)b * Ss + srow) * Dd + h * DK;
        const float qe = Q[g + e];       // lane e holds Q[row][e]
        float accv = 0.f, qsum = 0.f;
#pragma unroll
        for (int d = 0; d < 64; ++d) {
            const float qd = __shfl(qe, d, 64);   // broadcast Q[row][d]
            qsum += qd;
            accv = fmaf(qd, kvs[d][e], accv);
        }
        const float norm = 1.f / (qsum * ks + 1e-6f);
        O[g + e] = accv * norm;
    }
}

// ---------------------------------------------------------------------------
extern "C" void kernel_launch(void* const* d_in, const int* in_sizes, int n_in,
                              void* d_out, int out_size, void* d_ws, size_t ws_size,
                              hipStream_t stream)
{
    const float* q  = (const float*)d_in[0];
    const float* k  = (const float*)d_in[1];
    const float* v  = (const float*)d_in[2];
    const float* Wq = (const float*)d_in[3];
    const float* Wk = (const float*)d_in[4];
    const float* Wv = (const float*)d_in[5];
    const float* Wo = (const float*)d_in[6];
    float* out = (float*)d_out;

    const size_t A = (size_t)Mrows * Dd;
    float* Qb   = (float*)d_ws;
    float* Kb   = Qb + A;
    float* Vb   = Kb + A;
    float* kvb  = Vb + A;
    float* ksb  = kvb + (size_t)Bb * Hh * DK * DK;
    float* Omid = Kb;   // reuse K's buffer after kv_kernel consumed it

    dim3 gg(Mrows / 128, Dd / 128);
    gemm_xt<1><<<gg, 256, 0, stream>>>(q, Wq, Qb, Mrows, Dd, Dd);
    gemm_xt<1><<<gg, 256, 0, stream>>>(k, Wk, Kb, Mrows, Dd, Dd);
    gemm_xt<0><<<gg, 256, 0, stream>>>(v, Wv, Vb, Mrows, Dd, Dd);

    hipMemsetAsync(kvb, 0, ((size_t)Bb * Hh * DK * DK + Bb * Hh) * sizeof(float),
                   stream);
    kv_kernel<<<dim3(Bb * Hh, Ss / CH2), 256, 0, stream>>>(Kb, Vb, kvb, ksb);
    qkv_norm_kernel<<<dim3(Bb * Hh, Ss / 64), 256, 0, stream>>>(Qb, kvb, ksb, Omid);

    gemm_xt<0><<<gg, 256, 0, stream>>>(Omid, Wo, out, Mrows, Dd, Dd);
}